// Round 9
// baseline (184.208 us; speedup 1.0000x reference)
//
#include <hip/hip_runtime.h>
#include <stdint.h>

// QuantizedLinear: out[N,OUT_F] = requant(int8gemm(x, W^T) + bias)
// x: [8192,4096] int8 (pushed int32), W: [4096,4096] int8 (pushed int32)
// out: int8 values stored as int32 (harness reads d_out as np.int32)
//
// r9: ALL 12 prefetch ds_reads issued at tile top BEFORE the 16-MFMA burst
// (r8 had 6 of them sandwiched between MFMA clusters -> wave issue-stall on
// busy matrix pipe delayed them -> LDS and MFMA bursts alternated instead of
// overlapping). Otherwise identical to r8: register-prefetch pipeline,
// 4-slot LDS ring, one barrier/tile, counted vmcnt(4), setprio, XCD swizzle.

#define M_DIM 8192
#define N_DIM 4096
#define K_DIM 4096
#define BM 256
#define BN 256
#define NKT2 (K_DIM / 32)            // 128 k-subtiles in panel layout
#define NT (K_DIM / 64)              // 64 K-tiles (2 subtiles each)
#define NBLK ((M_DIM / BM) * (N_DIM / BN))   // 512
#define ABUF (BM * 64)               // 16 KiB per slot
#define BBUF (BN * 64)               // 16 KiB per slot

using i32x4  = __attribute__((ext_vector_type(4))) int;
using i32x16 = __attribute__((ext_vector_type(16))) int;

typedef const __attribute__((address_space(1))) uint32_t* gptr_t;
typedef __attribute__((address_space(3))) uint32_t* lptr_t;

__device__ __forceinline__ void gload_lds16(const void* g, void* l) {
    __builtin_amdgcn_global_load_lds((gptr_t)g, (lptr_t)l, 16, 0, 0);
}

__device__ __forceinline__ int pack4(i32x4 v) {
    return (int)(((unsigned)v.x & 0xFFu) | (((unsigned)v.y & 0xFFu) << 8) |
                 (((unsigned)v.z & 0xFFu) << 16) | (((unsigned)v.w) << 24));
}

// int32 [rows][K_DIM] -> fragment-ordered panels [rows/32][NKT2][1024]
// block (rb,kt): byte[l*16+j] = (int8)src[rb*32 + (l&31)][kt*32 + (l>>5)*16 + j]
__global__ void pack_panels32_kernel(const int* __restrict__ src, int8_t* __restrict__ dst,
                                     int n_blocks) {
    int gid = blockIdx.x * blockDim.x + threadIdx.x;
    int blk = gid >> 6;
    int l = gid & 63;
    if (blk >= n_blocks) return;
    int rb = blk >> 7;               // / NKT2
    int kt = blk & (NKT2 - 1);
    const i32x4* s4 = (const i32x4*)(src + (size_t)(rb * 32 + (l & 31)) * K_DIM
                                         + kt * 32 + (l >> 5) * 16);
    i32x4 o;
    o.x = pack4(s4[0]); o.y = pack4(s4[1]); o.z = pack4(s4[2]); o.w = pack4(s4[3]);
    *(i32x4*)(dst + (size_t)blk * 1024 + l * 16) = o;
}

#define MFMA32(a, b, c) __builtin_amdgcn_mfma_i32_32x32x32_i8((a), (b), (c), 0, 0, 0)

// Lane-linear fragment reads; bases include wave offset + lane*16.
// All slot/r/c/k offsets are compile-time immediates (max 56320 < 64K).
#define RA(S, R, K) (*(const i32x4*)(Ard + (S) * ABUF + (R) * 2048 + (K) * 1024))
#define RB(S, C, K) (*(const i32x4*)(Brd + (S) * BBUF + (C) * 2048 + (K) * 1024))

// Read one k-half of next tile's fragments into set NS (no consumer this tile).
#define READ_HALF(NS, SLOT, K)                                          \
    fA[NS][K][0] = RA(SLOT, 0, K); fA[NS][K][1] = RA(SLOT, 1, K);       \
    fA[NS][K][2] = RA(SLOT, 2, K); fA[NS][K][3] = RA(SLOT, 3, K);       \
    fB[NS][K][0] = RB(SLOT, 0, K); fB[NS][K][1] = RB(SLOT, 1, K);

// 8 independent MFMAs on set CS, k-half K.
#define MFMA_HALF(CS, K)                                                          \
    acc[0][0] = MFMA32(fA[CS][K][0], fB[CS][K][0], acc[0][0]);                    \
    acc[0][1] = MFMA32(fA[CS][K][0], fB[CS][K][1], acc[0][1]);                    \
    acc[1][0] = MFMA32(fA[CS][K][1], fB[CS][K][0], acc[1][0]);                    \
    acc[1][1] = MFMA32(fA[CS][K][1], fB[CS][K][1], acc[1][1]);                    \
    acc[2][0] = MFMA32(fA[CS][K][2], fB[CS][K][0], acc[2][0]);                    \
    acc[2][1] = MFMA32(fA[CS][K][2], fB[CS][K][1], acc[2][1]);                    \
    acc[3][0] = MFMA32(fA[CS][K][3], fB[CS][K][0], acc[3][0]);                    \
    acc[3][1] = MFMA32(fA[CS][K][3], fB[CS][K][1], acc[3][1]);

// Stage tile into slot (4 gload_lds/wave), advance running global pointers.
#define STAGE(SLOT)                                                     \
    gload_lds16(AgS,        ldsA + (SLOT) * ABUF + waoff);              \
    gload_lds16(AgS + 1024, ldsA + (SLOT) * ABUF + waoff + 1024);       \
    gload_lds16(BgS,        ldsB + (SLOT) * BBUF + waoff);              \
    gload_lds16(BgS + 1024, ldsB + (SLOT) * BBUF + waoff + 1024);       \
    AgS += 2048; BgS += 2048;

// Steady-state tile: stage t+2; sync t+1 landed; issue ALL 12 prefetch reads
// for t+1; then the full 16-MFMA burst for t (reads drain on LDS pipe
// concurrently with the matrix pipe).
#define TILE_STEADY(SLOT_STG, SLOT_NXT, CS, NS)                         \
  { STAGE(SLOT_STG)                                                     \
    asm volatile("s_waitcnt vmcnt(4)" ::: "memory");                    \
    __builtin_amdgcn_s_barrier();                                       \
    READ_HALF(NS, SLOT_NXT, 0)                                          \
    READ_HALF(NS, SLOT_NXT, 1)                                          \
    __builtin_amdgcn_sched_barrier(0);                                  \
    __builtin_amdgcn_s_setprio(1);                                      \
    MFMA_HALF(CS, 0)                                                    \
    MFMA_HALF(CS, 1)                                                    \
    __builtin_amdgcn_s_setprio(0); }

__global__ __launch_bounds__(512, 2)
void qgemm32_kernel(const int8_t* __restrict__ xp, const int8_t* __restrict__ wp,
                    const int* __restrict__ bias, const float* __restrict__ wscale,
                    const float* __restrict__ iscale, const float* __restrict__ oscale,
                    const int* __restrict__ zp, int* __restrict__ out) {
    extern __shared__ int8_t lds[];
    int8_t* ldsA = lds;               // 4 slots * 16 KiB, [rsub 0..7][ksub 0..1][1024]
    int8_t* ldsB = lds + 4 * ABUF;    // 4 slots * 16 KiB, [csub 0..7][ksub 0..1][1024]

    const int tid  = threadIdx.x;
    const int wave = tid >> 6;
    const int lane = tid & 63;

    // XCD-bijective swizzle (NBLK = 512, divisible by 8)
    int b = blockIdx.x;
    int s = (b & 7) * (NBLK >> 3) + (b >> 3);
    const int bcol = (s & 15) * BN;   // N_DIM/BN = 16
    const int brow = (s >> 4) * BM;

    const int wr = wave >> 2;         // 0..1  (M half, 128 rows = 4 rsubs)
    const int wc = wave & 3;          // 0..3  (N quarter, 64 cols = 2 csubs)

    // staging sources (fragment-ordered panels; advance 2048 B per K-tile)
    const int rb0 = brow >> 5;
    const int cb0 = bcol >> 5;
    const int8_t* AgS = xp + ((size_t)(rb0 + wave) * NKT2) * 1024 + lane * 16;
    const int8_t* BgS = wp + ((size_t)(cb0 + wave) * NKT2) * 1024 + lane * 16;
    const int waoff = wave * 2048;

    // fragment read bases (all else folds into ds_read offset immediates)
    const int8_t* Ard = ldsA + wr * 8192 + lane * 16;
    const int8_t* Brd = ldsB + wc * 4096 + lane * 16;

    i32x16 acc[4][2] = {};
    i32x4 fA[2][2][4];                // [set][khalf][rsub] — all indices static
    i32x4 fB[2][2][2];                // [set][khalf][csub]

    // ---- prologue: stage tile0->slot0, tile1->slot1; land tile0; read set0 ----
    STAGE(0)
    STAGE(1)
    asm volatile("s_waitcnt vmcnt(4)" ::: "memory");   // tile0 landed
    __builtin_amdgcn_s_barrier();
    READ_HALF(0, 0, 0)
    READ_HALF(0, 0, 1)

    // ---- main loop: 15 iterations x 4 tiles (t = 0..59), staging t+2 ----
    for (int i = 0; i < 15; ++i) {
        TILE_STEADY(2, 1, 0, 1)       // t%4==0: stage slot2, next slot1
        TILE_STEADY(3, 2, 1, 0)       // t%4==1
        TILE_STEADY(0, 3, 0, 1)       // t%4==2
        TILE_STEADY(1, 0, 1, 0)       // t%4==3
    }
    // ---- t=60: stage 62->slot2 ---- / ---- t=61: stage 63->slot3 ----
    TILE_STEADY(2, 1, 0, 1)
    TILE_STEADY(3, 2, 1, 0)
    // ---- t=62: no stage; drain; prefetch tile63 (slot3); MFMA tile62 (set0) ----
    {
        asm volatile("s_waitcnt vmcnt(0)" ::: "memory");
        __builtin_amdgcn_s_barrier();
        READ_HALF(1, 3, 0)
        READ_HALF(1, 3, 1)
        __builtin_amdgcn_sched_barrier(0);
        __builtin_amdgcn_s_setprio(1);
        MFMA_HALF(0, 0)
        MFMA_HALF(0, 1)
        __builtin_amdgcn_s_setprio(0);
    }
    // ---- t=63: final MFMA (set1) ----
    MFMA_HALF(1, 0)
    MFMA_HALF(1, 1)

    // ---- epilogue: out = clip(round((acc + bias) * (is*ws/os) + zp)) as int32 ----
    // 32x32 C/D layout (HW-verified): col = lane&31, row = (reg&3) + 8*(reg>>2) + 4*(lane>>5)
    const float is_v = iscale[0];
    const float os_v = oscale[0];
    const float zpf = (float)zp[0];
    #pragma unroll
    for (int c = 0; c < 2; c++) {
        int col = bcol + wc * 64 + c * 32 + (lane & 31);
        float sf = (is_v * wscale[col]) / os_v;
        int bz = bias[col];
        #pragma unroll
        for (int r = 0; r < 4; r++) {
            int rowb = brow + wr * 128 + r * 32 + 4 * (lane >> 5);
            #pragma unroll
            for (int reg = 0; reg < 16; reg++) {
                int row = rowb + (reg & 3) + 8 * (reg >> 2);
                float v = (float)(acc[r][c][reg] + bz) * sf + zpf;
                v = rintf(v);
                v = fminf(fmaxf(v, -128.0f), 127.0f);
                out[(size_t)row * N_DIM + col] = (int)v;
            }
        }
    }
}

#define MFMA_I8(a, b, c) __builtin_amdgcn_mfma_i32_16x16x64_i8((a), (b), (c), 0, 0, 0)

// Fallback (no workspace): direct int32 consumption, 128^2 tile (round-2 proven).
__global__ void qgemm_fallback(const int* __restrict__ x32, const int* __restrict__ w32,
                               const int* __restrict__ bias, const float* __restrict__ wscale,
                               const float* __restrict__ iscale, const float* __restrict__ oscale,
                               const int* __restrict__ zp, int* __restrict__ out) {
    __shared__ int8_t As[128][64];
    __shared__ int8_t Bs[128][64];
    const int tid  = threadIdx.x;
    const int wave = tid >> 6;
    const int lane = tid & 63;
    int b = blockIdx.x;
    int s = (b & 7) * (gridDim.x >> 3) + (b >> 3);
    const int bcol = (s & 31) * 128;
    const int brow = (s >> 5) * 128;
    const int wr = wave >> 1;
    const int wc = wave & 1;
    i32x4 acc[4][4] = {};
    for (int kt = 0; kt < K_DIM; kt += 64) {
        int row = tid >> 1;
        int h = tid & 1;
        const i32x4* sa = (const i32x4*)(x32 + (size_t)(brow + row) * K_DIM + kt + h * 32);
        const i32x4* sb = (const i32x4*)(w32 + (size_t)(bcol + row) * K_DIM + kt + h * 32);
        int pa[8], pb[8];
        #pragma unroll
        for (int j = 0; j < 8; j++) { pa[j] = pack4(sa[j]); pb[j] = pack4(sb[j]); }
        *(i32x4*)&As[row][h * 32]      = *(i32x4*)&pa[0];
        *(i32x4*)&As[row][h * 32 + 16] = *(i32x4*)&pa[4];
        *(i32x4*)&Bs[row][h * 32]      = *(i32x4*)&pb[0];
        *(i32x4*)&Bs[row][h * 32 + 16] = *(i32x4*)&pb[4];
        __syncthreads();
        i32x4 a_frag[4], b_frag[4];
        #pragma unroll
        for (int m = 0; m < 4; m++)
            a_frag[m] = *(const i32x4*)&As[wr * 64 + m * 16 + (lane & 15)][(lane >> 4) * 16];
        #pragma unroll
        for (int n = 0; n < 4; n++)
            b_frag[n] = *(const i32x4*)&Bs[wc * 64 + n * 16 + (lane & 15)][(lane >> 4) * 16];
        #pragma unroll
        for (int m = 0; m < 4; m++)
            #pragma unroll
            for (int n = 0; n < 4; n++)
                acc[m][n] = MFMA_I8(a_frag[m], b_frag[n], acc[m][n]);
        __syncthreads();
    }
    const float is_v = iscale[0];
    const float os_v = oscale[0];
    const float zpf = (float)zp[0];
    #pragma unroll
    for (int n = 0; n < 4; n++) {
        int col = bcol + wc * 64 + n * 16 + (lane & 15);
        float sf = (is_v * wscale[col]) / os_v;
        int bz = bias[col];
        #pragma unroll
        for (int m = 0; m < 4; m++) {
            int row0 = brow + wr * 64 + m * 16 + (lane >> 4) * 4;
            #pragma unroll
            for (int r = 0; r < 4; r++) {
                float v = (float)(acc[m][n][r] + bz) * sf + zpf;
                v = rintf(v);
                v = fminf(fmaxf(v, -128.0f), 127.0f);
                out[(size_t)(row0 + r) * N_DIM + col] = (int)v;
            }
        }
    }
}

extern "C" void kernel_launch(void* const* d_in, const int* in_sizes, int n_in,
                              void* d_out, int out_size, void* d_ws, size_t ws_size,
                              hipStream_t stream) {
    const int*   x32    = (const int*)d_in[0];
    const int*   w32    = (const int*)d_in[1];
    const int*   bias   = (const int*)d_in[2];
    const float* wscale = (const float*)d_in[3];
    const float* iscale = (const float*)d_in[4];
    const float* oscale = (const float*)d_in[5];
    const int*   zp     = (const int*)d_in[6];
    int* out = (int*)d_out;

    const size_t need = (size_t)M_DIM * K_DIM + (size_t)N_DIM * K_DIM;  // 50.3 MB
    const size_t lds_bytes = 4 * (size_t)(ABUF + BBUF);                 // 131072

    if (ws_size >= need) {
        int8_t* xp = (int8_t*)d_ws;
        int8_t* wp = xp + (size_t)M_DIM * K_DIM;
        const int nblkA = (M_DIM / 32) * NKT2;   // 32768
        const int nblkB = (N_DIM / 32) * NKT2;   // 16384
        pack_panels32_kernel<<<nblkA / 4, 256, 0, stream>>>(x32, xp, nblkA);
        pack_panels32_kernel<<<nblkB / 4, 256, 0, stream>>>(w32, wp, nblkB);
        (void)hipFuncSetAttribute((const void*)qgemm32_kernel,
                                  hipFuncAttributeMaxDynamicSharedMemorySize,
                                  (int)lds_bytes);
        qgemm32_kernel<<<NBLK, 512, lds_bytes, stream>>>(xp, wp, bias, wscale, iscale, oscale, zp, out);
    } else {
        qgemm_fallback<<<2048, 256, 0, stream>>>(x32, w32, bias, wscale, iscale, oscale, zp, out);
    }
}